// Round 12
// baseline (59.631 us; speedup 1.0000x reference)
//
#include <hip/hip_runtime.h>
#include <stdint.h>

#define OUT_F 8192
#define IN_F  8192
#define NGRP  1048576            // OUT*IN/GS
#define BATCH 64
#define KC    16                 // total split-K chunks (512 k each)
#define KCHUNK 512
#define NSTEP 16                 // 16 steps of k=32 per wave

typedef float f32x4 __attribute__((ext_vector_type(4)));
typedef _Float16 half8_t __attribute__((ext_vector_type(8)));

static __device__ __forceinline__ unsigned int pk_fma_f16(unsigned int a, unsigned int b, unsigned int c) {
  unsigned int d;
  asm("v_pk_fma_f16 %0, %1, %2, %3" : "=v"(d) : "v"(a), "v"(b), "v"(c));
  return d;
}
static __device__ __forceinline__ unsigned int pk16(float a, float b) {
  unsigned short ua = __builtin_bit_cast(unsigned short, (_Float16)a);
  unsigned short ub = __builtin_bit_cast(unsigned short, (_Float16)b);
  return (unsigned int)ua | ((unsigned int)ub << 16);
}

#define GLL16(g, l)                                                         \
  __builtin_amdgcn_global_load_lds(                                         \
      (const __attribute__((address_space(1))) void*)(g),                   \
      (__attribute__((address_space(3))) void*)(l), 16, 0, 0)

// ---- fused pre-pass: x fp32->f16  +  per-2-group {f16x2(s), f16x2(-(64+z)s)} ----
__global__ __launch_bounds__(256) void pre_kernel(const float* __restrict__ x, ushort* __restrict__ xh,
                                                  const float* __restrict__ scale, const float* __restrict__ zero,
                                                  uint32_t* __restrict__ szb) {
  const int b = blockIdx.x;
  if (b < 512) {                      // 512*256 = BATCH*IN_F/4
    const int i = b * 256 + threadIdx.x;
    float4 v = ((const float4*)x)[i];
    ushort4 o;
    o.x = __builtin_bit_cast(unsigned short, (_Float16)v.x);
    o.y = __builtin_bit_cast(unsigned short, (_Float16)v.y);
    o.z = __builtin_bit_cast(unsigned short, (_Float16)v.z);
    o.w = __builtin_bit_cast(unsigned short, (_Float16)v.w);
    ((ushort4*)xh)[i] = o;
  } else {                            // 1024*256 = NGRP/4
    const int i = (b - 512) * 256 + threadIdx.x;
    float4 s = ((const float4*)scale)[i];
    float4 z = ((const float4*)zero)[i];
    uint4 o;
    o.x = pk16(s.x, s.y);
    o.y = pk16(-(64.f + z.x) * s.x, -(64.f + z.y) * s.y);
    o.z = pk16(s.z, s.w);
    o.w = pk16(-(64.f + z.z) * s.z, -(64.f + z.w) * s.w);
    ((uint4*)szb)[i] = o;
  }
}

// ---- main fused dequant + GEMM: ZERO barriers, fully wave-private dataflow ----
// grid 1024: c = bid>>3, kp = bid&7. Wave wid: gq = wid&1, kc = kp*2 + (wid>>1).
// Lane (tr=lane&15, l4=lane>>4): owns Wq row gq*16+tr, k-octet l4 -> its own MFMA
// B-fragment. Hi nibble -> o=(gq*16+tr)*128+c, lo -> +4096. All 64 m per wave.
// W: per-wave private LDS quad-buffer [4][16 rows][32 ints], slot^row XOR swizzle,
//    staged 2 iters ahead via global_load_lds (2 gll/step) -> compiler cannot sink.
// sz: per-wave 2 KB staged once in prologue. A(x): bracketed compiler half8 loads, L2-hit.
__global__ __launch_bounds__(256, 4) void hqq_gemm_kernel(
    const int* __restrict__ Wq, const uint32_t* __restrict__ szb,
    const ushort* __restrict__ xh, float* __restrict__ part)
{
  __shared__ unsigned wlds[4][4][16 * 32];   // [wave][buf][row*32+int] : 32 KB
  __shared__ unsigned szlds[4][512];         // [wave][k] : 8 KB

  const int t    = threadIdx.x;
  const int bid  = blockIdx.x;
  const int kp   = bid & 7;
  const int c    = bid >> 3;
  const int wid  = t >> 6;
  const int lane = t & 63;
  const int gq   = wid & 1;
  const int kc   = kp * 2 + (wid >> 1);
  const int tr   = lane & 15;
  const int l4   = lane >> 4;
  const int kbase = kc * KCHUNK;

  // W staging source (pre-swizzled): gll0 covers rows 0..7, gll1 rows 8..15.
  // LDS(row rt, slot u) = global(rt, u ^ rt&7);  lane -> rt = lane>>3 (&7), u = lane&7.
  const int srow = lane >> 3;          // 0..7
  const int sslot = lane & 7;
  const int* __restrict__ wsrc0 =
      Wq + (size_t)(gq * 16 + srow) * NGRP + (size_t)c * IN_F + kbase + ((sslot ^ srow) * 4);
  const int* __restrict__ wsrc1 = wsrc0 + (size_t)8 * NGRP;

  const uint8_t* __restrict__ szsrc =
      (const uint8_t*)szb + ((size_t)c * IN_F + kbase) * 4;

  const ushort* __restrict__ xl = xh + (size_t)tr * IN_F + kbase + l4 * 8;

  f32x4 acc[2][4];
  #pragma unroll
  for (int nn = 0; nn < 2; ++nn)
    #pragma unroll
    for (int m = 0; m < 4; ++m) acc[nn][m] = (f32x4){0.f, 0.f, 0.f, 0.f};

  half8_t ar[2][4];   // A double-buffer (static indexing after full unroll)

#define STAGE_W(bi, s)  do {                                            \
    GLL16(wsrc0 + (size_t)(s) * 32, &wlds[wid][bi][0]);                 \
    GLL16(wsrc1 + (size_t)(s) * 32, &wlds[wid][bi][8 * 32]);            \
  } while (0)
#define LDA(set, s)  do { _Pragma("unroll")                             \
    for (int mq = 0; mq < 4; ++mq)                                      \
      ar[set][mq] = *(const half8_t*)(xl + (size_t)mq * (16 * IN_F) + (s) * 32); \
  } while (0)

  // ---- prologue: sz (2 gll), W(0), W(1) (4 gll), A(0) (4 loads) ----
  GLL16(szsrc + lane * 16, &szlds[wid][0]);
  GLL16(szsrc + 1024 + lane * 16, &szlds[wid][256]);
  STAGE_W(0, 0);
  STAGE_W(1, 1);
  asm volatile("" ::: "memory");
  LDA(0, 0);
  asm volatile("" ::: "memory");

  #pragma unroll
  for (int s = 0; s < NSTEP; ++s) {
    // issue next A, then next-next W (order matters for vmcnt accounting)
    if (s + 1 < NSTEP) LDA((s + 1) & 1, s + 1);
    asm volatile("" ::: "memory");
    if (s + 2 < NSTEP) STAGE_W((s + 2) & 3, s + 2);

    // retire A(s) and W(s) (+sz at s==0); leave W(s+1), A(s+1), W(s+2) in flight
    if (s == 0)             asm volatile("s_waitcnt vmcnt(6)" ::: "memory");
    else if (s <= NSTEP - 3) asm volatile("s_waitcnt vmcnt(8)" ::: "memory");
    else if (s == NSTEP - 2) asm volatile("s_waitcnt vmcnt(6)" ::: "memory");
    else                    asm volatile("s_waitcnt vmcnt(0)" ::: "memory");
    __builtin_amdgcn_sched_barrier(0);

    // ds_read W (swizzled, 2-way max) + sz (broadcast)
    const uint8_t* wb = (const uint8_t*)&wlds[wid][s & 3][0];
    const uint8_t* zb = (const uint8_t*)&szlds[wid][0];
    uint4 q0 = *(const uint4*)(wb + tr * 128 + (((2 * l4) ^ (tr & 7)) << 4));
    uint4 q1 = *(const uint4*)(wb + tr * 128 + (((2 * l4 + 1) ^ (tr & 7)) << 4));
    uint4 sa = *(const uint4*)(zb + s * 128 + l4 * 32);
    uint4 sb = *(const uint4*)(zb + s * 128 + l4 * 32 + 16);

    // dequant: f16 magic 0x5400|(v<<4) == 64+v (nibble at mantissa [7:4])
    union { uint4 u; half8_t h; } uh, ul;
    {
      unsigned tt = ((unsigned)q0.y << 16) | (unsigned)q0.x;
      uh.u.x = pk_fma_f16((tt & 0x00F000F0u) | 0x54005400u, sa.x, sa.y);
      ul.u.x = pk_fma_f16(((tt << 4) & 0x00F000F0u) | 0x54005400u, sa.x, sa.y);
    }
    {
      unsigned tt = ((unsigned)q0.w << 16) | (unsigned)q0.z;
      uh.u.y = pk_fma_f16((tt & 0x00F000F0u) | 0x54005400u, sa.z, sa.w);
      ul.u.y = pk_fma_f16(((tt << 4) & 0x00F000F0u) | 0x54005400u, sa.z, sa.w);
    }
    {
      unsigned tt = ((unsigned)q1.y << 16) | (unsigned)q1.x;
      uh.u.z = pk_fma_f16((tt & 0x00F000F0u) | 0x54005400u, sb.x, sb.y);
      ul.u.z = pk_fma_f16(((tt << 4) & 0x00F000F0u) | 0x54005400u, sb.x, sb.y);
    }
    {
      unsigned tt = ((unsigned)q1.w << 16) | (unsigned)q1.z;
      uh.u.w = pk_fma_f16((tt & 0x00F000F0u) | 0x54005400u, sb.z, sb.w);
      ul.u.w = pk_fma_f16(((tt << 4) & 0x00F000F0u) | 0x54005400u, sb.z, sb.w);
    }
    const half8_t bhi = uh.h;
    const half8_t blo = ul.h;

    #pragma unroll
    for (int mq = 0; mq < 4; ++mq) {
      acc[0][mq] = __builtin_amdgcn_mfma_f32_16x16x32_f16(ar[s & 1][mq], bhi, acc[0][mq], 0, 0, 0);
      acc[1][mq] = __builtin_amdgcn_mfma_f32_16x16x32_f16(ar[s & 1][mq], blo, acc[1][mq], 0, 0, 0);
    }
  }
#undef STAGE_W
#undef LDA

  // epilogue: C/D col = lane&15 -> o-row, row = (lane>>4)*4 + j -> m
  const int o_hi = (gq * 16 + tr) * 128 + c;
  const int msub = l4 * 4;
  float* p0 = part + ((size_t)kc * OUT_F + o_hi) * BATCH + msub;
  float* p1 = part + ((size_t)kc * OUT_F + o_hi + 4096) * BATCH + msub;
  #pragma unroll
  for (int mq = 0; mq < 4; ++mq) {
    *(float4*)(p0 + mq * 16) = (float4){acc[0][mq][0], acc[0][mq][1], acc[0][mq][2], acc[0][mq][3]};
    *(float4*)(p1 + mq * 16) = (float4){acc[1][mq][0], acc[1][mq][1], acc[1][mq][2], acc[1][mq][3]};
  }
}

// ---- split-K reduce + bias + transpose to out[m][o] ----
__global__ __launch_bounds__(256) void reduce_kernel(const float* __restrict__ part,
                                                     const float* __restrict__ bias,
                                                     float* __restrict__ out)
{
  __shared__ float tile[32][65];
  const int ob = blockIdx.x;          // o-range [ob*32, +32)
  const int t  = threadIdx.x;
  {
    const int ol = t >> 3;            // 0..31
    const int mg = t & 7;             // m-octet
    const int o  = ob * 32 + ol;
    const size_t base = (size_t)o * BATCH + mg * 8;
    float s[8] = {0, 0, 0, 0, 0, 0, 0, 0};
    #pragma unroll
    for (int kc = 0; kc < KC; ++kc) {
      const float* p = part + (size_t)kc * OUT_F * BATCH + base;
      float4 a = *(const float4*)p;
      float4 b = *(const float4*)(p + 4);
      s[0] += a.x; s[1] += a.y; s[2] += a.z; s[3] += a.w;
      s[4] += b.x; s[5] += b.y; s[6] += b.z; s[7] += b.w;
    }
    const float bv = bias[o];
    #pragma unroll
    for (int j = 0; j < 8; ++j) tile[ol][mg * 8 + j] = s[j] + bv;
  }
  __syncthreads();
  {
    const int m  = t >> 2;            // 0..63
    const int og = (t & 3) * 8;       // 0..31
    float r[8];
    #pragma unroll
    for (int j = 0; j < 8; ++j) r[j] = tile[og + j][m];
    float* op = out + (size_t)m * OUT_F + ob * 32 + og;
    *(float4*)op       = (float4){r[0], r[1], r[2], r[3]};
    *(float4*)(op + 4) = (float4){r[4], r[5], r[6], r[7]};
  }
}

// ---- correctness fallback (tiny ws), fp32 ----
__global__ void hqq_fallback_kernel(const float* __restrict__ x, const int* __restrict__ Wq,
                                    const float* __restrict__ scale, const float* __restrict__ zero,
                                    const float* __restrict__ bias, float* __restrict__ out)
{
  int idx = blockIdx.x * blockDim.x + threadIdx.x;
  int b = idx >> 13;
  int o = idx & 8191;
  int g = o >> 7, cc = o & 127;
  int r = g & 31;
  bool hi = (g < 32);
  const int*   wrow = Wq    + (size_t)r  * NGRP + (size_t)cc * IN_F;
  const float* srow = scale + (size_t)cc * IN_F;
  const float* zrow = zero  + (size_t)cc * IN_F;
  const float* xrow = x     + (size_t)b  * IN_F;
  float acc = 0.f;
  for (int k = 0; k < IN_F; ++k) {
    int v = wrow[k];
    float nib = (float)(hi ? (v >> 4) : (v & 15));
    acc += xrow[k] * ((nib - zrow[k]) * srow[k]);
  }
  out[idx] = acc + bias[o];
}

extern "C" void kernel_launch(void* const* d_in, const int* in_sizes, int n_in,
                              void* d_out, int out_size, void* d_ws, size_t ws_size,
                              hipStream_t stream) {
  const float* x     = (const float*)d_in[0];
  const int*   Wq    = (const int*)d_in[1];
  const float* scale = (const float*)d_in[2];
  const float* zero  = (const float*)d_in[3];
  const float* bias  = (const float*)d_in[4];
  float* out = (float*)d_out;

  const size_t xh_bytes   = (size_t)BATCH * IN_F * sizeof(ushort);        // 1 MB
  const size_t sz_bytes   = (size_t)NGRP * 4;                             // 4 MB
  const size_t part_bytes = (size_t)KC * BATCH * OUT_F * sizeof(float);   // 32 MB

  if (ws_size >= xh_bytes + sz_bytes + part_bytes) {
    ushort*   xh   = (ushort*)d_ws;
    uint32_t* szb  = (uint32_t*)((char*)d_ws + xh_bytes);
    float*    part = (float*)((char*)d_ws + xh_bytes + sz_bytes);
    pre_kernel<<<1536, 256, 0, stream>>>(x, xh, scale, zero, szb);
    hqq_gemm_kernel<<<128 * 8, 256, 0, stream>>>(Wq, szb, xh, part);
    reduce_kernel<<<OUT_F / 32, 256, 0, stream>>>(part, bias, out);
  } else {
    hqq_fallback_kernel<<<(BATCH * OUT_F) / 256, 256, 0, stream>>>(x, Wq, scale, zero, bias, out);
  }
}

// Round 14
// 42.153 us; speedup vs baseline: 1.4146x; 1.4146x over previous
//
#include <hip/hip_runtime.h>
#include <stdint.h>

#define OUT_F 8192
#define IN_F  8192
#define NGRP  1048576      // OUT*IN/GS
#define BATCH 64
#define KS    4
#define NSTEP ((IN_F / KS) / 128)   // 16

typedef float f32x4 __attribute__((ext_vector_type(4)));
typedef _Float16 half8_t __attribute__((ext_vector_type(8)));

static __device__ __forceinline__ unsigned int pk_fma_f16(unsigned int a, unsigned int b, unsigned int c) {
  unsigned int d;
  asm("v_pk_fma_f16 %0, %1, %2, %3" : "=v"(d) : "v"(a), "v"(b), "v"(c));
  return d;
}
static __device__ __forceinline__ unsigned int pk16(float a, float b) {
  unsigned short ua = __builtin_bit_cast(unsigned short, (_Float16)a);
  unsigned short ub = __builtin_bit_cast(unsigned short, (_Float16)b);
  return (unsigned int)ua | ((unsigned int)ub << 16);
}

#define GLL16(g, l)                                                         \
  __builtin_amdgcn_global_load_lds(                                         \
      (const __attribute__((address_space(1))) void*)(g),                   \
      (__attribute__((address_space(3))) void*)(l), 16, 0, 0)

// ---- fused pre-pass: x fp32->f16  +  per-2-group {f16x2(s), f16x2(-(64+z)s)} ----
__global__ __launch_bounds__(256) void pre_kernel(const float* __restrict__ x, ushort* __restrict__ xh,
                                                  const float* __restrict__ scale, const float* __restrict__ zero,
                                                  uint32_t* __restrict__ szb) {
  const int b = blockIdx.x;
  if (b < 512) {                      // 512*256 = BATCH*IN_F/4
    const int i = b * 256 + threadIdx.x;
    float4 v = ((const float4*)x)[i];
    ushort4 o;
    o.x = __builtin_bit_cast(unsigned short, (_Float16)v.x);
    o.y = __builtin_bit_cast(unsigned short, (_Float16)v.y);
    o.z = __builtin_bit_cast(unsigned short, (_Float16)v.z);
    o.w = __builtin_bit_cast(unsigned short, (_Float16)v.w);
    ((ushort4*)xh)[i] = o;
  } else {                            // 1024*256 = NGRP/4
    const int i = (b - 512) * 256 + threadIdx.x;
    float4 s = ((const float4*)scale)[i];
    float4 z = ((const float4*)zero)[i];
    uint4 o;
    o.x = pk16(s.x, s.y);
    o.y = pk16(-(64.f + z.x) * s.x, -(64.f + z.y) * s.y);
    o.z = pk16(s.z, s.w);
    o.w = pk16(-(64.f + z.z) * s.z, -(64.f + z.w) * s.w);
    ((uint4*)szb)[i] = o;
  }
}

// ---- main fused dequant + GEMM (R6 skeleton, full 64-output column tile) ----
// grid 512: ks = bid&3 (2048 k each), c = bid>>2. Block owns ALL 64 outputs of column c:
// B-tile rows g=0..63: g<32 -> hi nibble of Wq row g; g>=32 -> lo nibble of Wq row g-32.
// x: wave-private rows, triple-buffered LDS via gll. W: 32 rows reg-load + fused dequant
// -> ds_write double-buffered B tile. sz: registers (1 uint4/thread/step, amortizes 4 rows).
__global__ __launch_bounds__(256, 2) void hqq_gemm_kernel(
    const int* __restrict__ Wq, const uint32_t* __restrict__ szb,
    const ushort* __restrict__ xh, float* __restrict__ part)
{
  __shared__ ushort xlds[3][64 * 128];   // 16 KB each
  __shared__ ushort blds[2][64 * 128];   // 16 KB each (dequanted B tile, 64 rows)

  const int t    = threadIdx.x;
  const int bid  = blockIdx.x;
  const int ks   = bid & 3;
  const int c    = bid >> 2;
  const int lane = t & 63;
  const int wid  = t >> 6;
  const int kbase = ks * (IN_F / KS);

  // staging ids: lr = t>>5 (0..7) covers Wq rows lr, lr+8, lr+16, lr+24; i0 = 4 k-ints
  const int lr = t >> 5;
  const int i0 = (t & 31) * 4;
  const int* __restrict__ wq0 = Wq + (size_t)lr * NGRP + (size_t)c * IN_F + kbase + i0;
  const int* __restrict__ wq1 = wq0 + (size_t)8 * NGRP;
  const int* __restrict__ wq2 = wq0 + (size_t)16 * NGRP;
  const int* __restrict__ wq3 = wq0 + (size_t)24 * NGRP;
  const uint8_t* __restrict__ szp =
      (const uint8_t*)szb + ((size_t)c * IN_F + kbase + i0) * 4;
  const int wb0 = (i0 * 2) ^ ((lr & 7) << 4);   // swizzled write byte col (8B aligned)

  // frag ids
  const int tr    = lane & 15;
  const int koff8 = (lane >> 4) * 8;
  const int am    = wid * 16 + tr;

  f32x4 acc0 = {0.f, 0.f, 0.f, 0.f};
  f32x4 acc1 = {0.f, 0.f, 0.f, 0.f};
  f32x4 acc2 = {0.f, 0.f, 0.f, 0.f};
  f32x4 acc3 = {0.f, 0.f, 0.f, 0.f};

  // x: 4 gll, wave-private rows; source pre-swizzled: LDS[m][b] = x[m][b^((m&7)<<4)]
  auto stage_x = [&](int bi, int s) {
    #pragma unroll
    for (int j = 0; j < 4; ++j) {
      const int m    = wid * 16 + j * 4 + (lane >> 4);
      const int scol = ((lane & 15) * 16) ^ ((m & 7) << 4);
      const ushort* g = xh + (size_t)m * IN_F + kbase + s * 128 + (scol >> 1);
      GLL16(g, &xlds[bi][(wid * 16 + j * 4) * 128]);
    }
  };

  auto ldregs = [&](int s, int4& w0, int4& w1, int4& w2, int4& w3, uint4& z4) {
    w0 = *(const int4*)(wq0 + (size_t)s * 128);
    w1 = *(const int4*)(wq1 + (size_t)s * 128);
    w2 = *(const int4*)(wq2 + (size_t)s * 128);
    w3 = *(const int4*)(wq3 + (size_t)s * 128);
    z4 = *(const uint4*)(szp + (size_t)s * 512);
  };

  // f16 magic: 0x5400 | (v<<4) == 64+v  (nibble at mantissa bits [7:4])
  auto stage_b = [&](int bi, const int4& w0, const int4& w1, const int4& w2, const int4& w3,
                     const uint4& z4) {
    uint8_t* bb = (uint8_t*)&blds[bi][0];
    auto dqrow = [&](const int4& wv, int r) {
      unsigned tt0 = ((unsigned)wv.y << 16) | (unsigned)wv.x;
      unsigned tt1 = ((unsigned)wv.w << 16) | (unsigned)wv.z;
      uint2 hh, ll;
      hh.x = pk_fma_f16((tt0 & 0x00F000F0u) | 0x54005400u, z4.x, z4.y);
      hh.y = pk_fma_f16((tt1 & 0x00F000F0u) | 0x54005400u, z4.z, z4.w);
      ll.x = pk_fma_f16(((tt0 << 4) & 0x00F000F0u) | 0x54005400u, z4.x, z4.y);
      ll.y = pk_fma_f16(((tt1 << 4) & 0x00F000F0u) | 0x54005400u, z4.z, z4.w);
      *(uint2*)(bb + r * 256 + wb0)        = hh;   // hi nibble row r
      *(uint2*)(bb + (r + 32) * 256 + wb0) = ll;   // lo nibble row r+32
    };
    dqrow(w0, lr);
    dqrow(w1, lr + 8);
    dqrow(w2, lr + 16);
    dqrow(w3, lr + 24);
  };

  // ---- prologue ----
  {
    int4 a0, a1, a2, a3; uint4 z0;
    ldregs(0, a0, a1, a2, a3, z0);
    stage_b(0, a0, a1, a2, a3, z0);   // compiler waits regs(0)
  }
  stage_x(0, 0);
  stage_x(1, 1);
  int4 w0, w1, w2, w3; uint4 z4;
  ldregs(1, w0, w1, w2, w3, z4);      // regs for stage_b(1)

  int xr0 = 0, xr1 = 1, xr2 = 2;

  #pragma unroll 1
  for (int s = 0; s < NSTEP; ++s) {
    // retire compute(s-1) on all waves; make stage_b(s) ds_writes visible.
    asm volatile("s_waitcnt lgkmcnt(0)" ::: "memory");
    __builtin_amdgcn_s_barrier();

    const bool more2 = (s + 2 < NSTEP);
    int4 n0, n1, n2, n3; uint4 nz;
    if (more2) {
      stage_x(xr2, s + 2);               // 4 gll
      ldregs(s + 2, n0, n1, n2, n3, nz); // 5 reg loads
    }

    // in-order vmcnt: wait x(s); newer = [x(s+1)4 + regs(s+1)5] + [x(s+2)4 + regs(s+2)5]
    if (more2)               asm volatile("s_waitcnt vmcnt(18)" ::: "memory");
    else if (s + 1 < NSTEP)  asm volatile("s_waitcnt vmcnt(9)" ::: "memory");
    else                     asm volatile("s_waitcnt vmcnt(0)" ::: "memory");
    __builtin_amdgcn_sched_barrier(0);

    // compute(s): pure ds_read + MFMA; B rows tr, tr+16, tr+32, tr+48 (same swizzle col)
    const uint8_t* xb = (const uint8_t*)&xlds[xr0][0];
    const uint8_t* bbuf = (const uint8_t*)&blds[s & 1][0];
    #pragma unroll
    for (int kk = 0; kk < 4; ++kk) {
      const int colb = (koff8 + kk * 32) * 2;
      const int bcol = colb ^ ((tr & 7) << 4);
      half8_t a  = *(const half8_t*)(xb + am * 256 + (colb ^ ((am & 7) << 4)));
      half8_t b0 = *(const half8_t*)(bbuf + tr * 256 + bcol);
      half8_t b1 = *(const half8_t*)(bbuf + (tr + 16) * 256 + bcol);
      half8_t b2 = *(const half8_t*)(bbuf + (tr + 32) * 256 + bcol);
      half8_t b3 = *(const half8_t*)(bbuf + (tr + 48) * 256 + bcol);
      acc0 = __builtin_amdgcn_mfma_f32_16x16x32_f16(a, b0, acc0, 0, 0, 0);
      acc1 = __builtin_amdgcn_mfma_f32_16x16x32_f16(a, b1, acc1, 0, 0, 0);
      acc2 = __builtin_amdgcn_mfma_f32_16x16x32_f16(a, b2, acc2, 0, 0, 0);
      acc3 = __builtin_amdgcn_mfma_f32_16x16x32_f16(a, b3, acc3, 0, 0, 0);
    }

    // dequant + ds_write B(s+1); compiler inserts counted vmcnt for regs(s+1)
    if (s + 1 < NSTEP) stage_b((s + 1) & 1, w0, w1, w2, w3, z4);
    if (more2) { w0 = n0; w1 = n1; w2 = n2; w3 = n3; z4 = nz; }

    const int tmp = xr0; xr0 = xr1; xr1 = xr2; xr2 = tmp;
  }

  // epilogue: C/D col = lane&15 -> B row -> o = (tr+16f)*128+c; row -> m
  const int m0 = wid * 16 + (lane >> 4) * 4;
  float* base = part + (size_t)ks * OUT_F * BATCH + (size_t)m0;
  *(float4*)(base + (size_t)(tr * 128 + c) * BATCH)        = (float4){acc0[0], acc0[1], acc0[2], acc0[3]};
  *(float4*)(base + (size_t)((tr + 16) * 128 + c) * BATCH) = (float4){acc1[0], acc1[1], acc1[2], acc1[3]};
  *(float4*)(base + (size_t)((tr + 32) * 128 + c) * BATCH) = (float4){acc2[0], acc2[1], acc2[2], acc2[3]};
  *(float4*)(base + (size_t)((tr + 48) * 128 + c) * BATCH) = (float4){acc3[0], acc3[1], acc3[2], acc3[3]};
}

// ---- split-K reduce + bias + transpose to out[m][o] ----
__global__ __launch_bounds__(256) void reduce_kernel(const float* __restrict__ part,
                                                     const float* __restrict__ bias,
                                                     float* __restrict__ out)
{
  __shared__ float tile[32][65];
  const int ob = blockIdx.x;          // o-range [ob*32, +32)
  const int t  = threadIdx.x;
  {
    const int ol = t >> 3;            // 0..31
    const int mg = t & 7;             // m-octet
    const int o  = ob * 32 + ol;
    const size_t base = (size_t)o * BATCH + mg * 8;
    float s[8] = {0, 0, 0, 0, 0, 0, 0, 0};
    #pragma unroll
    for (int ks = 0; ks < KS; ++ks) {
      const float* p = part + (size_t)ks * OUT_F * BATCH + base;
      float4 a = *(const float4*)p;
      float4 b = *(const float4*)(p + 4);
      s[0] += a.x; s[1] += a.y; s[2] += a.z; s[3] += a.w;
      s[4] += b.x; s[5] += b.y; s[6] += b.z; s[7] += b.w;
    }
    const float bv = bias[o];
    #pragma unroll
    for (int j = 0; j < 8; ++j) tile[ol][mg * 8 + j] = s[j] + bv;
  }
  __syncthreads();
  {
    const int m  = t >> 2;            // 0..63
    const int og = (t & 3) * 8;       // 0..31
    float r[8];
    #pragma unroll
    for (int j = 0; j < 8; ++j) r[j] = tile[og + j][m];
    float* op = out + (size_t)m * OUT_F + ob * 32 + og;
    *(float4*)op       = (float4){r[0], r[1], r[2], r[3]};
    *(float4*)(op + 4) = (float4){r[4], r[5], r[6], r[7]};
  }
}

// ---- correctness fallback (tiny ws), fp32 ----
__global__ void hqq_fallback_kernel(const float* __restrict__ x, const int* __restrict__ Wq,
                                    const float* __restrict__ scale, const float* __restrict__ zero,
                                    const float* __restrict__ bias, float* __restrict__ out)
{
  int idx = blockIdx.x * blockDim.x + threadIdx.x;
  int b = idx >> 13;
  int o = idx & 8191;
  int g = o >> 7, cc = o & 127;
  int r = g & 31;
  bool hi = (g < 32);
  const int*   wrow = Wq    + (size_t)r  * NGRP + (size_t)cc * IN_F;
  const float* srow = scale + (size_t)cc * IN_F;
  const float* zrow = zero  + (size_t)cc * IN_F;
  const float* xrow = x     + (size_t)b  * IN_F;
  float acc = 0.f;
  for (int k = 0; k < IN_F; ++k) {
    int v = wrow[k];
    float nib = (float)(hi ? (v >> 4) : (v & 15));
    acc += xrow[k] * ((nib - zrow[k]) * srow[k]);
  }
  out[idx] = acc + bias[o];
}

extern "C" void kernel_launch(void* const* d_in, const int* in_sizes, int n_in,
                              void* d_out, int out_size, void* d_ws, size_t ws_size,
                              hipStream_t stream) {
  const float* x     = (const float*)d_in[0];
  const int*   Wq    = (const int*)d_in[1];
  const float* scale = (const float*)d_in[2];
  const float* zero  = (const float*)d_in[3];
  const float* bias  = (const float*)d_in[4];
  float* out = (float*)d_out;

  const size_t xh_bytes   = (size_t)BATCH * IN_F * sizeof(ushort);        // 1 MB
  const size_t sz_bytes   = (size_t)NGRP * 4;                             // 4 MB
  const size_t part_bytes = (size_t)KS * BATCH * OUT_F * sizeof(float);   // 8 MB

  if (ws_size >= xh_bytes + sz_bytes + part_bytes) {
    ushort*   xh   = (ushort*)d_ws;
    uint32_t* szb  = (uint32_t*)((char*)d_ws + xh_bytes);
    float*    part = (float*)((char*)d_ws + xh_bytes + sz_bytes);
    pre_kernel<<<1536, 256, 0, stream>>>(x, xh, scale, zero, szb);
    hqq_gemm_kernel<<<128 * KS, 256, 0, stream>>>(Wq, szb, xh, part);
    reduce_kernel<<<OUT_F / 32, 256, 0, stream>>>(part, bias, out);
  } else {
    hqq_fallback_kernel<<<(BATCH * OUT_F) / 256, 256, 0, stream>>>(x, Wq, scale, zero, bias, out);
  }
}

// Round 15
// 42.005 us; speedup vs baseline: 1.4196x; 1.0035x over previous
//
#include <hip/hip_runtime.h>
#include <stdint.h>

#define OUT_F 8192
#define IN_F  8192
#define NGRP  1048576      // OUT*IN/GS
#define BATCH 64
#define KS    4
#define NSTEP ((IN_F / KS) / 128)   // 16

typedef float f32x4  __attribute__((ext_vector_type(4)));
typedef float f32x16 __attribute__((ext_vector_type(16)));
typedef _Float16 half8_t __attribute__((ext_vector_type(8)));

static __device__ __forceinline__ unsigned int pk_fma_f16(unsigned int a, unsigned int b, unsigned int c) {
  unsigned int d;
  asm("v_pk_fma_f16 %0, %1, %2, %3" : "=v"(d) : "v"(a), "v"(b), "v"(c));
  return d;
}
static __device__ __forceinline__ unsigned int pk16(float a, float b) {
  unsigned short ua = __builtin_bit_cast(unsigned short, (_Float16)a);
  unsigned short ub = __builtin_bit_cast(unsigned short, (_Float16)b);
  return (unsigned int)ua | ((unsigned int)ub << 16);
}

#define GLL16(g, l)                                                         \
  __builtin_amdgcn_global_load_lds(                                         \
      (const __attribute__((address_space(1))) void*)(g),                   \
      (__attribute__((address_space(3))) void*)(l), 16, 0, 0)

// ---- fused pre-pass: x fp32->f16  +  per-2-group {f16x2(s), f16x2(-(64+z)s)} ----
__global__ __launch_bounds__(256) void pre_kernel(const float* __restrict__ x, ushort* __restrict__ xh,
                                                  const float* __restrict__ scale, const float* __restrict__ zero,
                                                  uint32_t* __restrict__ szb) {
  const int b = blockIdx.x;
  if (b < 512) {                      // 512*256 = BATCH*IN_F/4
    const int i = b * 256 + threadIdx.x;
    float4 v = ((const float4*)x)[i];
    ushort4 o;
    o.x = __builtin_bit_cast(unsigned short, (_Float16)v.x);
    o.y = __builtin_bit_cast(unsigned short, (_Float16)v.y);
    o.z = __builtin_bit_cast(unsigned short, (_Float16)v.z);
    o.w = __builtin_bit_cast(unsigned short, (_Float16)v.w);
    ((ushort4*)xh)[i] = o;
  } else {                            // 1024*256 = NGRP/4
    const int i = (b - 512) * 256 + threadIdx.x;
    float4 s = ((const float4*)scale)[i];
    float4 z = ((const float4*)zero)[i];
    uint4 o;
    o.x = pk16(s.x, s.y);
    o.y = pk16(-(64.f + z.x) * s.x, -(64.f + z.y) * s.y);
    o.z = pk16(s.z, s.w);
    o.w = pk16(-(64.f + z.z) * s.z, -(64.f + z.w) * s.w);
    ((uint4*)szb)[i] = o;
  }
}

// ---- main fused dequant + GEMM (R14 skeleton; 32x32x16 MFMA wave-quadrants) ----
// grid 512: ks = bid&3 (2048 k each), c = bid>>2. Block owns ALL 64 outputs of column c.
// Wave quadrant: mh = wid&1 (32 m rows), nh = wid>>1 (32 B rows). Per step (128 k):
// 8 k-slices of 16; per slice one ds_read_b128 A + one B + one 32x32x16 MFMA.
__global__ __launch_bounds__(256, 2) void hqq_gemm_kernel(
    const int* __restrict__ Wq, const uint32_t* __restrict__ szb,
    const ushort* __restrict__ xh, float* __restrict__ part)
{
  __shared__ ushort xlds[3][64 * 128];   // 16 KB each
  __shared__ ushort blds[2][64 * 128];   // 16 KB each (dequanted B tile, 64 rows)

  const int t    = threadIdx.x;
  const int bid  = blockIdx.x;
  const int ks   = bid & 3;
  const int c    = bid >> 2;
  const int lane = t & 63;
  const int wid  = t >> 6;
  const int kbase = ks * (IN_F / KS);

  // staging ids: lr = t>>5 (0..7) covers Wq rows lr, lr+8, lr+16, lr+24; i0 = 4 k-ints
  const int lr = t >> 5;
  const int i0 = (t & 31) * 4;
  const int* __restrict__ wq0 = Wq + (size_t)lr * NGRP + (size_t)c * IN_F + kbase + i0;
  const int* __restrict__ wq1 = wq0 + (size_t)8 * NGRP;
  const int* __restrict__ wq2 = wq0 + (size_t)16 * NGRP;
  const int* __restrict__ wq3 = wq0 + (size_t)24 * NGRP;
  const uint8_t* __restrict__ szp =
      (const uint8_t*)szb + ((size_t)c * IN_F + kbase + i0) * 4;
  const int wb0 = (i0 * 2) ^ ((lr & 7) << 4);   // swizzled write byte col (8B aligned)

  // frag ids (32x32 quadrants)
  const int mh   = wid & 1;
  const int nh   = wid >> 1;
  const int ln31 = lane & 31;
  const int koct = lane >> 5;           // 0/1 -> k sub-octet
  const int arow = mh * 32 + ln31;      // x row (m)
  const int brow = nh * 32 + ln31;      // B-tile row (o)

  f32x16 acc = {0.f, 0.f, 0.f, 0.f, 0.f, 0.f, 0.f, 0.f,
                0.f, 0.f, 0.f, 0.f, 0.f, 0.f, 0.f, 0.f};

  // x: 4 gll, staged by wave wid for rows wid*16..+15 (readers may be other waves;
  // visibility guaranteed: each wave's stage_b(s+1) operand-wait drains its x(s+1)
  // glls in-order before the barrier that opens compute(s+1)).
  auto stage_x = [&](int bi, int s) {
    #pragma unroll
    for (int j = 0; j < 4; ++j) {
      const int m    = wid * 16 + j * 4 + (lane >> 4);
      const int scol = ((lane & 15) * 16) ^ ((m & 7) << 4);
      const ushort* g = xh + (size_t)m * IN_F + kbase + s * 128 + (scol >> 1);
      GLL16(g, &xlds[bi][(wid * 16 + j * 4) * 128]);
    }
  };

  auto ldregs = [&](int s, int4& w0, int4& w1, int4& w2, int4& w3, uint4& z4) {
    w0 = *(const int4*)(wq0 + (size_t)s * 128);
    w1 = *(const int4*)(wq1 + (size_t)s * 128);
    w2 = *(const int4*)(wq2 + (size_t)s * 128);
    w3 = *(const int4*)(wq3 + (size_t)s * 128);
    z4 = *(const uint4*)(szp + (size_t)s * 512);
  };

  // f16 magic: 0x5400 | (v<<4) == 64+v  (nibble at mantissa bits [7:4])
  auto stage_b = [&](int bi, const int4& w0, const int4& w1, const int4& w2, const int4& w3,
                     const uint4& z4) {
    uint8_t* bb = (uint8_t*)&blds[bi][0];
    auto dqrow = [&](const int4& wv, int r) {
      unsigned tt0 = ((unsigned)wv.y << 16) | (unsigned)wv.x;
      unsigned tt1 = ((unsigned)wv.w << 16) | (unsigned)wv.z;
      uint2 hh, ll;
      hh.x = pk_fma_f16((tt0 & 0x00F000F0u) | 0x54005400u, z4.x, z4.y);
      hh.y = pk_fma_f16((tt1 & 0x00F000F0u) | 0x54005400u, z4.z, z4.w);
      ll.x = pk_fma_f16(((tt0 << 4) & 0x00F000F0u) | 0x54005400u, z4.x, z4.y);
      ll.y = pk_fma_f16(((tt1 << 4) & 0x00F000F0u) | 0x54005400u, z4.z, z4.w);
      *(uint2*)(bb + r * 256 + wb0)        = hh;   // hi nibble row r
      *(uint2*)(bb + (r + 32) * 256 + wb0) = ll;   // lo nibble row r+32
    };
    dqrow(w0, lr);
    dqrow(w1, lr + 8);
    dqrow(w2, lr + 16);
    dqrow(w3, lr + 24);
  };

  // ---- prologue ----
  {
    int4 a0, a1, a2, a3; uint4 z0;
    ldregs(0, a0, a1, a2, a3, z0);
    stage_b(0, a0, a1, a2, a3, z0);   // compiler waits regs(0)
  }
  stage_x(0, 0);
  stage_x(1, 1);
  int4 w0, w1, w2, w3; uint4 z4;
  ldregs(1, w0, w1, w2, w3, z4);      // regs for stage_b(1)

  int xr0 = 0, xr1 = 1, xr2 = 2;

  #pragma unroll 1
  for (int s = 0; s < NSTEP; ++s) {
    // retire compute(s-1) on all waves; make stage_b(s) ds_writes visible.
    asm volatile("s_waitcnt lgkmcnt(0)" ::: "memory");
    __builtin_amdgcn_s_barrier();

    const bool more2 = (s + 2 < NSTEP);
    int4 n0, n1, n2, n3; uint4 nz;
    if (more2) {
      stage_x(xr2, s + 2);               // 4 gll
      ldregs(s + 2, n0, n1, n2, n3, nz); // 5 reg loads
    }

    // in-order vmcnt: wait x(s); newer = [x(s+1)4 + regs(s+1)5] + [x(s+2)4 + regs(s+2)5]
    if (more2)               asm volatile("s_waitcnt vmcnt(18)" ::: "memory");
    else if (s + 1 < NSTEP)  asm volatile("s_waitcnt vmcnt(9)" ::: "memory");
    else                     asm volatile("s_waitcnt vmcnt(0)" ::: "memory");
    __builtin_amdgcn_sched_barrier(0);

    // compute(s): 8 k-slices; 1 A + 1 B ds_read_b128 + 1 32x32x16 MFMA each
    const uint8_t* xb   = (const uint8_t*)&xlds[xr0][0];
    const uint8_t* bbuf = (const uint8_t*)&blds[s & 1][0];
    #pragma unroll
    for (int kk = 0; kk < 8; ++kk) {
      const int colb = (kk * 16 + koct * 8) * 2;
      half8_t a = *(const half8_t*)(xb   + arow * 256 + (colb ^ ((arow & 7) << 4)));
      half8_t b = *(const half8_t*)(bbuf + brow * 256 + (colb ^ ((brow & 7) << 4)));
      acc = __builtin_amdgcn_mfma_f32_32x32x16_f16(a, b, acc, 0, 0, 0);
    }

    // dequant + ds_write B(s+1); compiler inserts counted vmcnt for regs(s+1)
    if (s + 1 < NSTEP) stage_b((s + 1) & 1, w0, w1, w2, w3, z4);
    if (more2) { w0 = n0; w1 = n1; w2 = n2; w3 = n3; z4 = nz; }

    const int tmp = xr0; xr0 = xr1; xr1 = xr2; xr2 = tmp;
  }

  // epilogue: 32x32 C/D layout: col = lane&31 -> B row -> o; row = (reg&3)+8*(reg>>2)+4*koct
  const int o = ln31 * 128 + c + nh * 4096;
  const int mbase = mh * 32 + 4 * koct;
  float* bp = part + ((size_t)ks * OUT_F + o) * BATCH + mbase;
  #pragma unroll
  for (int q = 0; q < 4; ++q) {
    *(float4*)(bp + 8 * q) = (float4){acc[4 * q], acc[4 * q + 1], acc[4 * q + 2], acc[4 * q + 3]};
  }
}

// ---- split-K reduce + bias + transpose to out[m][o] ----
__global__ __launch_bounds__(256) void reduce_kernel(const float* __restrict__ part,
                                                     const float* __restrict__ bias,
                                                     float* __restrict__ out)
{
  __shared__ float tile[32][65];
  const int ob = blockIdx.x;          // o-range [ob*32, +32)
  const int t  = threadIdx.x;
  {
    const int ol = t >> 3;            // 0..31
    const int mg = t & 7;             // m-octet
    const int o  = ob * 32 + ol;
    const size_t base = (size_t)o * BATCH + mg * 8;
    float s[8] = {0, 0, 0, 0, 0, 0, 0, 0};
    #pragma unroll
    for (int ks = 0; ks < KS; ++ks) {
      const float* p = part + (size_t)ks * OUT_F * BATCH + base;
      float4 a = *(const float4*)p;
      float4 b = *(const float4*)(p + 4);
      s[0] += a.x; s[1] += a.y; s[2] += a.z; s[3] += a.w;
      s[4] += b.x; s[5] += b.y; s[6] += b.z; s[7] += b.w;
    }
    const float bv = bias[o];
    #pragma unroll
    for (int j = 0; j < 8; ++j) tile[ol][mg * 8 + j] = s[j] + bv;
  }
  __syncthreads();
  {
    const int m  = t >> 2;            // 0..63
    const int og = (t & 3) * 8;       // 0..31
    float r[8];
    #pragma unroll
    for (int j = 0; j < 8; ++j) r[j] = tile[og + j][m];
    float* op = out + (size_t)m * OUT_F + ob * 32 + og;
    *(float4*)op       = (float4){r[0], r[1], r[2], r[3]};
    *(float4*)(op + 4) = (float4){r[4], r[5], r[6], r[7]};
  }
}

// ---- correctness fallback (tiny ws), fp32 ----
__global__ void hqq_fallback_kernel(const float* __restrict__ x, const int* __restrict__ Wq,
                                    const float* __restrict__ scale, const float* __restrict__ zero,
                                    const float* __restrict__ bias, float* __restrict__ out)
{
  int idx = blockIdx.x * blockDim.x + threadIdx.x;
  int b = idx >> 13;
  int o = idx & 8191;
  int g = o >> 7, cc = o & 127;
  int r = g & 31;
  bool hi = (g < 32);
  const int*   wrow = Wq    + (size_t)r  * NGRP + (size_t)cc * IN_F;
  const float* srow = scale + (size_t)cc * IN_F;
  const float* zrow = zero  + (size_t)cc * IN_F;
  const float* xrow = x     + (size_t)b  * IN_F;
  float acc = 0.f;
  for (int k = 0; k < IN_F; ++k) {
    int v = wrow[k];
    float nib = (float)(hi ? (v >> 4) : (v & 15));
    acc += xrow[k] * ((nib - zrow[k]) * srow[k]);
  }
  out[idx] = acc + bias[o];
}

extern "C" void kernel_launch(void* const* d_in, const int* in_sizes, int n_in,
                              void* d_out, int out_size, void* d_ws, size_t ws_size,
                              hipStream_t stream) {
  const float* x     = (const float*)d_in[0];
  const int*   Wq    = (const int*)d_in[1];
  const float* scale = (const float*)d_in[2];
  const float* zero  = (const float*)d_in[3];
  const float* bias  = (const float*)d_in[4];
  float* out = (float*)d_out;

  const size_t xh_bytes   = (size_t)BATCH * IN_F * sizeof(ushort);        // 1 MB
  const size_t sz_bytes   = (size_t)NGRP * 4;                             // 4 MB
  const size_t part_bytes = (size_t)KS * BATCH * OUT_F * sizeof(float);   // 8 MB

  if (ws_size >= xh_bytes + sz_bytes + part_bytes) {
    ushort*   xh   = (ushort*)d_ws;
    uint32_t* szb  = (uint32_t*)((char*)d_ws + xh_bytes);
    float*    part = (float*)((char*)d_ws + xh_bytes + sz_bytes);
    pre_kernel<<<1536, 256, 0, stream>>>(x, xh, scale, zero, szb);
    hqq_gemm_kernel<<<128 * KS, 256, 0, stream>>>(Wq, szb, xh, part);
    reduce_kernel<<<OUT_F / 32, 256, 0, stream>>>(part, bias, out);
  } else {
    hqq_fallback_kernel<<<(BATCH * OUT_F) / 256, 256, 0, stream>>>(x, Wq, scale, zero, bias, out);
  }
}

// Round 16
// 40.726 us; speedup vs baseline: 1.4642x; 1.0314x over previous
//
#include <hip/hip_runtime.h>
#include <stdint.h>

#define OUT_F 8192
#define IN_F  8192
#define NGRP  1048576      // OUT*IN/GS
#define BATCH 64
#define KS    4
#define NSTEP ((IN_F / KS) / 128)   // 16

typedef float f32x4  __attribute__((ext_vector_type(4)));
typedef float f32x16 __attribute__((ext_vector_type(16)));
typedef _Float16 half8_t __attribute__((ext_vector_type(8)));

static __device__ __forceinline__ unsigned int pk_fma_f16(unsigned int a, unsigned int b, unsigned int c) {
  unsigned int d;
  asm("v_pk_fma_f16 %0, %1, %2, %3" : "=v"(d) : "v"(a), "v"(b), "v"(c));
  return d;
}
static __device__ __forceinline__ unsigned int pk16(float a, float b) {
  unsigned short ua = __builtin_bit_cast(unsigned short, (_Float16)a);
  unsigned short ub = __builtin_bit_cast(unsigned short, (_Float16)b);
  return (unsigned int)ua | ((unsigned int)ub << 16);
}

#define GLL16(g, l)                                                         \
  __builtin_amdgcn_global_load_lds(                                         \
      (const __attribute__((address_space(1))) void*)(g),                   \
      (__attribute__((address_space(3))) void*)(l), 16, 0, 0)

// ---- fused pre-pass: x fp32->f16  +  per-2-group {f16x2(s), f16x2(-(64+z)s)} ----
__global__ __launch_bounds__(256) void pre_kernel(const float* __restrict__ x, ushort* __restrict__ xh,
                                                  const float* __restrict__ scale, const float* __restrict__ zero,
                                                  uint32_t* __restrict__ szb) {
  const int b = blockIdx.x;
  if (b < 512) {                      // 512*256 = BATCH*IN_F/4
    const int i = b * 256 + threadIdx.x;
    float4 v = ((const float4*)x)[i];
    ushort4 o;
    o.x = __builtin_bit_cast(unsigned short, (_Float16)v.x);
    o.y = __builtin_bit_cast(unsigned short, (_Float16)v.y);
    o.z = __builtin_bit_cast(unsigned short, (_Float16)v.z);
    o.w = __builtin_bit_cast(unsigned short, (_Float16)v.w);
    ((ushort4*)xh)[i] = o;
  } else {                            // 1024*256 = NGRP/4
    const int i = (b - 512) * 256 + threadIdx.x;
    float4 s = ((const float4*)scale)[i];
    float4 z = ((const float4*)zero)[i];
    uint4 o;
    o.x = pk16(s.x, s.y);
    o.y = pk16(-(64.f + z.x) * s.x, -(64.f + z.y) * s.y);
    o.z = pk16(s.z, s.w);
    o.w = pk16(-(64.f + z.z) * s.z, -(64.f + z.w) * s.w);
    ((uint4*)szb)[i] = o;
  }
}

// ---- main fused dequant + GEMM (R14 schedule; 512-thread block, 8 wave-octants) ----
// grid 512: ks = bid&3 (2048 k each), c = bid>>2. Block owns ALL 64 outputs of column c.
// Wave wid: kh = wid&1 (k-slices kh*4..+3), mh = (wid>>1)&1 (32 m), nh = wid>>2 (32 o).
// Final kh-pair sum via LDS scratch. 80 KB LDS -> 2 blocks/CU = 16 waves/CU.
__global__ __launch_bounds__(512, 4) void hqq_gemm_kernel(
    const int* __restrict__ Wq, const uint32_t* __restrict__ szb,
    const ushort* __restrict__ xh, float* __restrict__ part)
{
  __shared__ ushort xlds[3][64 * 128];   // 16 KB each
  __shared__ ushort blds[2][64 * 128];   // 16 KB each (B tile; reused as reduce scratch)

  const int t    = threadIdx.x;
  const int bid  = blockIdx.x;
  const int ks   = bid & 3;
  const int c    = bid >> 2;
  const int lane = t & 63;
  const int wid  = t >> 6;               // 0..7
  const int kbase = ks * (IN_F / KS);

  // staging ids: lr = t>>5 (0..15) covers Wq rows lr, lr+16; i0 = 4 k-ints
  const int lr = t >> 5;
  const int i0 = (t & 31) * 4;
  const int* __restrict__ wq0 = Wq + (size_t)lr * NGRP + (size_t)c * IN_F + kbase + i0;
  const int* __restrict__ wq1 = wq0 + (size_t)16 * NGRP;
  const uint8_t* __restrict__ szp =
      (const uint8_t*)szb + ((size_t)c * IN_F + kbase + i0) * 4;
  const int wb0 = (i0 * 2) ^ ((lr & 7) << 4);   // swizzled write byte col; (lr+16)&7==lr&7

  // frag ids (32x32 octants)
  const int kh   = wid & 1;
  const int mh   = (wid >> 1) & 1;
  const int nh   = wid >> 2;
  const int ln31 = lane & 31;
  const int koct = lane >> 5;
  const int arow = mh * 32 + ln31;
  const int brow = nh * 32 + ln31;

  f32x16 acc = {0.f, 0.f, 0.f, 0.f, 0.f, 0.f, 0.f, 0.f,
                0.f, 0.f, 0.f, 0.f, 0.f, 0.f, 0.f, 0.f};

  // x: 2 gll per wave, rows wid*8..+7; source pre-swizzled: LDS[m][b]=x[m][b^((m&7)<<4)]
  auto stage_x = [&](int bi, int s) {
    #pragma unroll
    for (int j = 0; j < 2; ++j) {
      const int m    = wid * 8 + j * 4 + (lane >> 4);
      const int scol = ((lane & 15) * 16) ^ ((m & 7) << 4);
      const ushort* g = xh + (size_t)m * IN_F + kbase + s * 128 + (scol >> 1);
      GLL16(g, &xlds[bi][(wid * 8 + j * 4) * 128]);
    }
  };

  auto ldregs = [&](int s, int4& w0, int4& w1, uint4& z4) {
    w0 = *(const int4*)(wq0 + (size_t)s * 128);
    w1 = *(const int4*)(wq1 + (size_t)s * 128);
    z4 = *(const uint4*)(szp + (size_t)s * 512);
  };

  // f16 magic: 0x5400 | (v<<4) == 64+v  (nibble at mantissa bits [7:4])
  auto stage_b = [&](int bi, const int4& w0, const int4& w1, const uint4& z4) {
    uint8_t* bb = (uint8_t*)&blds[bi][0];
    auto dqrow = [&](const int4& wv, int r) {
      unsigned tt0 = ((unsigned)wv.y << 16) | (unsigned)wv.x;
      unsigned tt1 = ((unsigned)wv.w << 16) | (unsigned)wv.z;
      uint2 hh, ll;
      hh.x = pk_fma_f16((tt0 & 0x00F000F0u) | 0x54005400u, z4.x, z4.y);
      hh.y = pk_fma_f16((tt1 & 0x00F000F0u) | 0x54005400u, z4.z, z4.w);
      ll.x = pk_fma_f16(((tt0 << 4) & 0x00F000F0u) | 0x54005400u, z4.x, z4.y);
      ll.y = pk_fma_f16(((tt1 << 4) & 0x00F000F0u) | 0x54005400u, z4.z, z4.w);
      *(uint2*)(bb + r * 256 + wb0)        = hh;   // hi nibble row r
      *(uint2*)(bb + (r + 32) * 256 + wb0) = ll;   // lo nibble row r+32
    };
    dqrow(w0, lr);
    dqrow(w1, lr + 16);
  };

  // ---- prologue ----
  {
    int4 a0, a1; uint4 z0;
    ldregs(0, a0, a1, z0);
    stage_b(0, a0, a1, z0);           // compiler waits regs(0)
  }
  stage_x(0, 0);
  stage_x(1, 1);
  int4 w0, w1; uint4 z4;
  ldregs(1, w0, w1, z4);              // regs for stage_b(1)

  int xr0 = 0, xr1 = 1, xr2 = 2;

  #pragma unroll 1
  for (int s = 0; s < NSTEP; ++s) {
    // retire compute(s-1) on all waves; make stage_b(s) ds_writes visible.
    asm volatile("s_waitcnt lgkmcnt(0)" ::: "memory");
    __builtin_amdgcn_s_barrier();

    const bool more2 = (s + 2 < NSTEP);
    int4 n0, n1; uint4 nz;
    if (more2) {
      stage_x(xr2, s + 2);            // 2 gll
      ldregs(s + 2, n0, n1, nz);      // 3 reg loads
    }

    // in-order vmcnt: wait x(s); newer = [x(s+1)2+regs(s+1)3] + [x(s+2)2+regs(s+2)3]
    if (more2)               asm volatile("s_waitcnt vmcnt(10)" ::: "memory");
    else if (s + 1 < NSTEP)  asm volatile("s_waitcnt vmcnt(5)" ::: "memory");
    else                     asm volatile("s_waitcnt vmcnt(0)" ::: "memory");
    __builtin_amdgcn_sched_barrier(0);

    // compute(s): wave's 4 k-slices; 1 A + 1 B ds_read_b128 + 1 32x32x16 MFMA each
    const uint8_t* xb   = (const uint8_t*)&xlds[xr0][0];
    const uint8_t* bbuf = (const uint8_t*)&blds[s & 1][0];
    #pragma unroll
    for (int j = 0; j < 4; ++j) {
      const int kk   = kh * 4 + j;
      const int colb = (kk * 16 + koct * 8) * 2;
      half8_t a = *(const half8_t*)(xb   + arow * 256 + (colb ^ ((arow & 7) << 4)));
      half8_t b = *(const half8_t*)(bbuf + brow * 256 + (colb ^ ((brow & 7) << 4)));
      acc = __builtin_amdgcn_mfma_f32_32x32x16_f16(a, b, acc, 0, 0, 0);
    }

    // dequant + ds_write B(s+1); compiler inserts counted vmcnt for regs(s+1)
    if (s + 1 < NSTEP) stage_b((s + 1) & 1, w0, w1, z4);
    if (more2) { w0 = n0; w1 = n1; z4 = nz; }

    const int tmp = xr0; xr0 = xr1; xr1 = xr2; xr2 = tmp;
  }

  // ---- kh-pair reduction via LDS scratch (blds = 32 KB, exactly fits 8x64x16 f32) ----
  __syncthreads();
  float* red = (float*)&blds[0][0];
  {
    float4* dst = (float4*)(red + ((size_t)(wid * 64 + lane)) * 16);
    dst[0] = (float4){acc[0],  acc[1],  acc[2],  acc[3]};
    dst[1] = (float4){acc[4],  acc[5],  acc[6],  acc[7]};
    dst[2] = (float4){acc[8],  acc[9],  acc[10], acc[11]};
    dst[3] = (float4){acc[12], acc[13], acc[14], acc[15]};
  }
  __syncthreads();
  if (kh == 0) {
    const float4* src = (const float4*)(red + ((size_t)((wid ^ 1) * 64 + lane)) * 16);
    float4 p0 = src[0], p1 = src[1], p2 = src[2], p3 = src[3];
    // 32x32 C/D: col = lane&31 -> B row -> o; row = (reg&3)+8*(reg>>2)+4*koct -> m
    const int o = ln31 * 128 + c + nh * 4096;
    const int mbase = mh * 32 + 4 * koct;
    float* bp = part + ((size_t)ks * OUT_F + o) * BATCH + mbase;
    *(float4*)(bp +  0) = (float4){acc[0]  + p0.x, acc[1]  + p0.y, acc[2]  + p0.z, acc[3]  + p0.w};
    *(float4*)(bp +  8) = (float4){acc[4]  + p1.x, acc[5]  + p1.y, acc[6]  + p1.z, acc[7]  + p1.w};
    *(float4*)(bp + 16) = (float4){acc[8]  + p2.x, acc[9]  + p2.y, acc[10] + p2.z, acc[11] + p2.w};
    *(float4*)(bp + 24) = (float4){acc[12] + p3.x, acc[13] + p3.y, acc[14] + p3.z, acc[15] + p3.w};
  }
}

// ---- split-K reduce + bias + transpose to out[m][o] ----
__global__ __launch_bounds__(256) void reduce_kernel(const float* __restrict__ part,
                                                     const float* __restrict__ bias,
                                                     float* __restrict__ out)
{
  __shared__ float tile[32][65];
  const int ob = blockIdx.x;          // o-range [ob*32, +32)
  const int t  = threadIdx.x;
  {
    const int ol = t >> 3;            // 0..31
    const int mg = t & 7;             // m-octet
    const int o  = ob * 32 + ol;
    const size_t base = (size_t)o * BATCH + mg * 8;
    float s[8] = {0, 0, 0, 0, 0, 0, 0, 0};
    #pragma unroll
    for (int ks = 0; ks < KS; ++ks) {
      const float* p = part + (size_t)ks * OUT_F * BATCH + base;
      float4 a = *(const float4*)p;
      float4 b = *(const float4*)(p + 4);
      s[0] += a.x; s[1] += a.y; s[2] += a.z; s[3] += a.w;
      s[4] += b.x; s[5] += b.y; s[6] += b.z; s[7] += b.w;
    }
    const float bv = bias[o];
    #pragma unroll
    for (int j = 0; j < 8; ++j) tile[ol][mg * 8 + j] = s[j] + bv;
  }
  __syncthreads();
  {
    const int m  = t >> 2;            // 0..63
    const int og = (t & 3) * 8;       // 0..31
    float r[8];
    #pragma unroll
    for (int j = 0; j < 8; ++j) r[j] = tile[og + j][m];
    float* op = out + (size_t)m * OUT_F + ob * 32 + og;
    *(float4*)op       = (float4){r[0], r[1], r[2], r[3]};
    *(float4*)(op + 4) = (float4){r[4], r[5], r[6], r[7]};
  }
}

// ---- correctness fallback (tiny ws), fp32 ----
__global__ void hqq_fallback_kernel(const float* __restrict__ x, const int* __restrict__ Wq,
                                    const float* __restrict__ scale, const float* __restrict__ zero,
                                    const float* __restrict__ bias, float* __restrict__ out)
{
  int idx = blockIdx.x * blockDim.x + threadIdx.x;
  int b = idx >> 13;
  int o = idx & 8191;
  int g = o >> 7, cc = o & 127;
  int r = g & 31;
  bool hi = (g < 32);
  const int*   wrow = Wq    + (size_t)r  * NGRP + (size_t)cc * IN_F;
  const float* srow = scale + (size_t)cc * IN_F;
  const float* zrow = zero  + (size_t)cc * IN_F;
  const float* xrow = x     + (size_t)b  * IN_F;
  float acc = 0.f;
  for (int k = 0; k < IN_F; ++k) {
    int v = wrow[k];
    float nib = (float)(hi ? (v >> 4) : (v & 15));
    acc += xrow[k] * ((nib - zrow[k]) * srow[k]);
  }
  out[idx] = acc + bias[o];
}

extern "C" void kernel_launch(void* const* d_in, const int* in_sizes, int n_in,
                              void* d_out, int out_size, void* d_ws, size_t ws_size,
                              hipStream_t stream) {
  const float* x     = (const float*)d_in[0];
  const int*   Wq    = (const int*)d_in[1];
  const float* scale = (const float*)d_in[2];
  const float* zero  = (const float*)d_in[3];
  const float* bias  = (const float*)d_in[4];
  float* out = (float*)d_out;

  const size_t xh_bytes   = (size_t)BATCH * IN_F * sizeof(ushort);        // 1 MB
  const size_t sz_bytes   = (size_t)NGRP * 4;                             // 4 MB
  const size_t part_bytes = (size_t)KS * BATCH * OUT_F * sizeof(float);   // 8 MB

  if (ws_size >= xh_bytes + sz_bytes + part_bytes) {
    ushort*   xh   = (ushort*)d_ws;
    uint32_t* szb  = (uint32_t*)((char*)d_ws + xh_bytes);
    float*    part = (float*)((char*)d_ws + xh_bytes + sz_bytes);
    pre_kernel<<<1536, 256, 0, stream>>>(x, xh, scale, zero, szb);
    hqq_gemm_kernel<<<128 * KS, 512, 0, stream>>>(Wq, szb, xh, part);
    reduce_kernel<<<OUT_F / 32, 256, 0, stream>>>(part, bias, out);
  } else {
    hqq_fallback_kernel<<<(BATCH * OUT_F) / 256, 256, 0, stream>>>(x, Wq, scale, zero, bias, out);
  }
}